// Round 1
// baseline (817.423 us; speedup 1.0000x reference)
//
#include <hip/hip_runtime.h>
#include <hip/hip_fp16.h>

#define Q 16
#define EPS 1e-8f
#define DEPTH 5

typedef unsigned int u32;
typedef _Float16 h2 __attribute__((ext_vector_type(2)));

__device__ __forceinline__ u32 pack2(float a, float b) {
    __half2 h = __floats2half2_rn(a, b);
    return *(u32*)&h;
}
__device__ __forceinline__ float2 unpack2(u32 u) {
    __half2 h = *(__half2*)&u;
    return __half22float2(h);
}
__device__ __forceinline__ h2 mkh2(float a, float b) {
    h2 v; v[0] = (_Float16)a; v[1] = (_Float16)b; return v;
}

// ========== one-time build: dst-sorted slots + consumer CSR (slot-major) ====
// Spaces: orig edge e in [0,E); slot j = pos[e] (dst-sorted).
// Consumer CSR: edge e consumes t2 row of producer p = indice[e].
// We store t2 in CONSUMER order: producer at slot j scatter-writes its row to
// each consumer's slot; next round reads t2c[j] streamed.

// lr[e]    = rank of e among edges with same dst (slot position)
// crank[e] = rank of e among consumers of producer indice[e]
__global__ __launch_bounds__(256) void rank0_kernel(
    const int* __restrict__ dst, const int* __restrict__ indice,
    int* __restrict__ count, int* __restrict__ ccount,
    int* __restrict__ lr, int* __restrict__ crank, int E)
{
    int e = blockIdx.x * 256 + threadIdx.x;
    if (e < E) {
        lr[e]    = atomicAdd(&count[dst[e]], 1);
        crank[e] = atomicAdd(&ccount[indice[e]], 1);
    }
}

// --- generic blocked exclusive scan (256/block); reused for N- and E-scans ---
__global__ __launch_bounds__(256) void scan_partial(
    const int* __restrict__ v, int* __restrict__ partial, int N)
{
    __shared__ int sm[256];
    int i = blockIdx.x * 256 + threadIdx.x;
    sm[threadIdx.x] = (i < N) ? v[i] : 0;
    __syncthreads();
    for (int off = 128; off > 0; off >>= 1) {
        if (threadIdx.x < off) sm[threadIdx.x] += sm[threadIdx.x + off];
        __syncthreads();
    }
    if (threadIdx.x == 0) partial[blockIdx.x] = sm[0];
}

__global__ __launch_bounds__(1024) void scan_top(
    int* __restrict__ partial, int nb)
{
    __shared__ int sm[1024];
    int t = threadIdx.x;
    int v = (t < nb) ? partial[t] : 0;
    sm[t] = v;
    __syncthreads();
    for (int off = 1; off < 1024; off <<= 1) {
        int u = (t >= off) ? sm[t - off] : 0;
        __syncthreads();
        sm[t] += u;
        __syncthreads();
    }
    if (t < nb) partial[t] = sm[t] - v;
}

__global__ __launch_bounds__(256) void scan_final(
    const int* __restrict__ v, const int* __restrict__ partial,
    int* __restrict__ out, int N)
{
    __shared__ int sm[256];
    int i = blockIdx.x * 256 + threadIdx.x;
    int x = (i < N) ? v[i] : 0;
    sm[threadIdx.x] = x;
    __syncthreads();
    for (int off = 1; off < 256; off <<= 1) {
        int u = (threadIdx.x >= off) ? sm[threadIdx.x - off] : 0;
        __syncthreads();
        sm[threadIdx.x] += u;
        __syncthreads();
    }
    int excl = sm[threadIdx.x] - x + partial[blockIdx.x];
    if (i < N) out[i] = excl;
    if (i == N - 1) out[N] = excl + x;
}

// pos[e] = start[dst[e]] + lr[e];  slotcc[slot of e] = #consumers of e
__global__ __launch_bounds__(256) void pos_kernel(
    const int* __restrict__ dst, const int* __restrict__ lr,
    const int* __restrict__ start, const int* __restrict__ ccount,
    int* __restrict__ pos, int* __restrict__ slotcc, int E)
{
    int e = blockIdx.x * 256 + threadIdx.x;
    if (e < E) {
        int p = start[dst[e]] + lr[e];
        pos[e] = p;
        slotcc[p] = ccount[e];
    }
}

// cons2[csl[pos[indice[e]]] + crank[e]] = pos[e]   (slot-major consumer lists)
__global__ __launch_bounds__(256) void cons_scatter(
    const int* __restrict__ indice, const int* __restrict__ crank,
    const int* __restrict__ pos, const int* __restrict__ csl,
    int* __restrict__ cons2, int E)
{
    int e = blockIdx.x * 256 + threadIdx.x;
    if (e < E) {
        int jp = pos[indice[e]];
        cons2[csl[jp] + crank[e]] = pos[e];
    }
}

// meta1[pos[e]] = dst<<16 | src ;  m0e[pos[e]] = e  (for round-1 cav gather)
__global__ __launch_bounds__(256) void scatter_direct(
    const int* __restrict__ a1_src, const int* __restrict__ dst,
    const int* __restrict__ pos,
    int* __restrict__ meta1, int* __restrict__ m0e, int E)
{
    int e = blockIdx.x * 256 + threadIdx.x;
    if (e < E) {
        int p = pos[e];
        meta1[p] = (int)(((u32)dst[e] << 16) | (u32)a1_src[e]);
        m0e[p]   = e;
    }
}

// boundary nodes: slot range crosses a 256-slot window, or empty.
__global__ __launch_bounds__(256) void bnode_build(
    const int* __restrict__ start, int* __restrict__ blist,
    int* __restrict__ bcount, int N)
{
    int n = blockIdx.x * 256 + threadIdx.x;
    if (n >= N) return;
    int slo = start[n], shi = start[n + 1];
    bool need = (slo == shi) || ((slo >> 8) != ((shi - 1) >> 8));
    if (need) {
        int p = atomicAdd(bcount, 1);
        blist[p] = n;
    }
}

// per-round: init only boundary-node rows to field
__global__ __launch_bounds__(256) void binit(
    const int* __restrict__ blist, const int* __restrict__ bcount,
    const float* __restrict__ field, float* __restrict__ marg)
{
    int idx = blockIdx.x * 256 + threadIdx.x;
    int cnt = *bcount;
    if (idx >= cnt * 4) return;
    int n = blist[idx >> 2], part = idx & 3;
    ((float4*)(marg + (size_t)n * Q))[part] =
        ((const float4*)(field + (size_t)n * Q))[part];
}

// ---------- fused per-round kernel ----------
// MODE 0: round 1 (reads cav via m0e gather), scatter-writes t2c
// MODE 1: mid rounds (STREAMED t2c_cur[j] read, marg gather), scatter t2c_next
// MODE 2: last round (as 1, no t2c write)
template<int MODE>
__global__ __launch_bounds__(256) void fused_round(
    const int* __restrict__ meta1, const int* __restrict__ m0e,
    const int* __restrict__ csl, const int* __restrict__ cons2,
    const float* __restrict__ C,
    const float* __restrict__ cav,
    const float* __restrict__ marg_in, const u32* __restrict__ t2c_cur,
    const int* __restrict__ start, const float* __restrict__ field,
    u32* __restrict__ t2c_next, float* __restrict__ marg_out, int E)
{
    __shared__ __align__(16) h2 Csh[Q * 8];   // column-major fp16
    __shared__ float stage[256 * 17];
    __shared__ int s_nfirst, s_nlast;

    const int tid = threadIdx.x;
    const int blo = blockIdx.x * 256;
    const int bhi = min(blo + 256, E);
    const int j = blo + tid;
    const bool act = (j < E);

    // ---- issue ALL global loads first ----
    int metav = 0, cs0 = 0, cs1 = 0;
    float4 m0, m1, m2, m3;
    uint4 r0, r1;
    if (act) {
        metav = meta1[j];
        if (MODE != 2) { cs0 = csl[j]; cs1 = csl[j + 1]; }   // streamed
        if (MODE == 0) {
            const float4* rp = (const float4*)(cav + (size_t)m0e[j] * Q);
            m0 = rp[0]; m1 = rp[1]; m2 = rp[2]; m3 = rp[3];
        } else {
            const int src = metav & 0xffff;
            const float4* mp = (const float4*)(marg_in + (size_t)src * Q);
            const uint4*  tp = (const uint4*)(t2c_cur + (size_t)j * 8); // STREAMED
            m0 = mp[0]; m1 = mp[1]; m2 = mp[2]; m3 = mp[3];
            r0 = tp[0]; r1 = tp[1];
        }
    }

    if (tid < 128) {
        int q = tid >> 3, kk = tid & 7;
        Csh[q * 8 + kk] = mkh2(C[(2 * kk) * Q + q], C[(2 * kk + 1) * Q + q]);
    }
    if (act) {
        int mydst = (int)(((u32)metav) >> 16);
        if (j == blo)     s_nfirst = mydst;
        if (j == bhi - 1) s_nlast  = mydst;
    }
    __syncthreads();

    float t[Q];
    if (act) {
        h2 uh[8];
        float s, logs;
        if (MODE == 0) {
            uh[0] = mkh2(m0.x, m0.y); uh[1] = mkh2(m0.z, m0.w);
            uh[2] = mkh2(m1.x, m1.y); uh[3] = mkh2(m1.z, m1.w);
            uh[4] = mkh2(m2.x, m2.y); uh[5] = mkh2(m2.z, m2.w);
            uh[6] = mkh2(m3.x, m3.y); uh[7] = mkh2(m3.z, m3.w);
            s = 1.f; logs = 0.f;
        } else {
            float2 p0 = unpack2(r0.x), p1 = unpack2(r0.y),
                   p2 = unpack2(r0.z), p3 = unpack2(r0.w);
            float2 p4 = unpack2(r1.x), p5 = unpack2(r1.y),
                   p6 = unpack2(r1.z), p7 = unpack2(r1.w);

            float x[Q] = {m0.x - p0.x, m0.y - p0.y, m0.z - p1.x, m0.w - p1.y,
                          m1.x - p2.x, m1.y - p2.y, m1.z - p3.x, m1.w - p3.y,
                          m2.x - p4.x, m2.y - p4.y, m2.z - p5.x, m2.w - p5.y,
                          m3.x - p6.x, m3.y - p6.y, m3.z - p7.x, m3.w - p7.y};

            float mx = x[0];
#pragma unroll
            for (int q = 1; q < Q; ++q) mx = fmaxf(mx, x[q]);
            float u[Q];
            s = 0.f;
#pragma unroll
            for (int q = 0; q < Q; ++q) { u[q] = __expf(x[q] - mx); s += u[q]; }
            logs = __logf(s);
#pragma unroll
            for (int k = 0; k < 8; ++k) uh[k] = mkh2(u[2 * k], u[2 * k + 1]);
        }

        const float base = EPS * s;
#pragma unroll
        for (int q = 0; q < Q; ++q) {
            const uint4* cp = (const uint4*)&Csh[q * 8];
            h2 col[8];
            ((uint4*)col)[0] = cp[0];
            ((uint4*)col)[1] = cp[1];
            float acc = base;
#pragma unroll
            for (int kk = 0; kk < 8; ++kk)
                acc = __builtin_amdgcn_fdot2(uh[kk], col[kk], acc, false);
            t[q] = __logf(acc) - logs;
        }

        if (MODE != 2) {
            uint4 w0, w1;
            w0.x = pack2(t[0],  t[1]);  w0.y = pack2(t[2],  t[3]);
            w0.z = pack2(t[4],  t[5]);  w0.w = pack2(t[6],  t[7]);
            w1.x = pack2(t[8],  t[9]);  w1.y = pack2(t[10], t[11]);
            w1.z = pack2(t[12], t[13]); w1.w = pack2(t[14], t[15]);
            // scatter to consumer slots (avg 1/slot); fire-and-forget writes
            for (int c = cs0; c < cs1; ++c) {
                uint4* op = (uint4*)(t2c_next + (size_t)cons2[c] * 8);
                op[0] = w0; op[1] = w1;
            }
        }
    } else {
#pragma unroll
        for (int q = 0; q < Q; ++q) t[q] = 0.f;
    }

#pragma unroll
    for (int q = 0; q < Q; ++q) stage[tid * 17 + q] = t[q];
    __syncthreads();

    const int nfirst = s_nfirst;
    const int ncnt = s_nlast - nfirst + 1;
    for (int k = tid; k < ncnt * Q; k += 256) {
        int ln = k >> 4, q = k & 15;
        int n = nfirst + ln;
        int slo = start[n], shi = start[n + 1];
        int lo = max(slo, blo), hi = min(shi, bhi);
        float s = 0.f;
        for (int sl = lo; sl < hi; ++sl) s += stage[(sl - blo) * 17 + q];
        if (slo >= blo && shi <= bhi)
            marg_out[(size_t)n * Q + q] = s + field[(size_t)n * Q + q];
        else
            atomicAdd(marg_out + (size_t)n * Q + q, s);
    }
}

// final: per node log_softmax
__global__ __launch_bounds__(256) void node_out(
    const float* __restrict__ marg, float* __restrict__ out, int N)
{
    int i = blockIdx.x * 256 + threadIdx.x;
    if (i >= N) return;

    const float4* mp = (const float4*)(marg + (size_t)i * Q);
    float4 m0 = mp[0], m1 = mp[1], m2 = mp[2], m3 = mp[3];
    float x[Q] = {m0.x, m0.y, m0.z, m0.w, m1.x, m1.y, m1.z, m1.w,
                  m2.x, m2.y, m2.z, m2.w, m3.x, m3.y, m3.z, m3.w};

    float mx = x[0];
#pragma unroll
    for (int q = 1; q < Q; ++q) mx = fmaxf(mx, x[q]);
    float s = 0.f;
#pragma unroll
    for (int q = 0; q < Q; ++q) s += __expf(x[q] - mx);
    float lse = mx + __logf(s);

    float4* op = (float4*)(out + (size_t)i * Q);
    op[0] = make_float4(x[0]  - lse, x[1]  - lse, x[2]  - lse, x[3]  - lse);
    op[1] = make_float4(x[4]  - lse, x[5]  - lse, x[6]  - lse, x[7]  - lse);
    op[2] = make_float4(x[8]  - lse, x[9]  - lse, x[10] - lse, x[11] - lse);
    op[3] = make_float4(x[12] - lse, x[13] - lse, x[14] - lse, x[15] - lse);
}

extern "C" void kernel_launch(void* const* d_in, const int* in_sizes, int n_in,
                              void* d_out, int out_size, void* d_ws, size_t ws_size,
                              hipStream_t stream) {
    // inputs: 0 marg_i (dead), 1 cav_ij, 2 C, 3 field_i, 4 edge_dst, 5 a1_src, 6 indice_ij
    const float* cav_in   = (const float*)d_in[1];
    const float* C        = (const float*)d_in[2];
    const float* field_i  = (const float*)d_in[3];
    const int*   edge_dst = (const int*)d_in[4];
    const int*   a1_src   = (const int*)d_in[5];
    const int*   indice   = (const int*)d_in[6];
    float* out = (float*)d_out;

    const int E = in_sizes[4];
    const int N = in_sizes[0] / Q;

    const int eb = 256;
    const int eg  = (E + eb - 1) / eb;      // blocks over E
    const int ng  = (N + eb - 1) / eb;      // blocks over N (<=1024 for scan_top)
    const int ng2 = (eg + eb - 1) / eb;     // second-level blocks for E-scan

    char* ws = (char*)d_ws;
    const size_t t2_bytes   = (size_t)E * 32;   // fp16 rows, 32B each
    const size_t node_bytes = (size_t)N * Q * sizeof(float);

    u32*   t2a    = (u32*)ws;               ws += t2_bytes;
    u32*   t2b    = (u32*)ws;               ws += t2_bytes;
    int*   meta1  = (int*)ws;               ws += (size_t)E * 4;
    int*   csl    = (int*)ws;               ws += (size_t)(E + 1) * 4;  // cstart_slot
    int*   ccount = (int*)ws;               ws += (size_t)E * 4;  // later: cons2
    int*   pos    = (int*)ws;               ws += (size_t)E * 4;
    int*   lr     = (int*)ws;               ws += (size_t)E * 4;  // later: m0e
    int*   crank  = (int*)ws;               ws += (size_t)E * 4;
    int*   slotcc = (int*)ws;               ws += (size_t)E * 4;
    float* marg_a = (float*)ws;             ws += node_bytes;
    float* marg_b = (float*)ws;             ws += node_bytes;
    int*   count  = (int*)ws;               ws += (size_t)N * 4;
    int*   bcount = (int*)ws;               ws += 4;
    int*   start  = (int*)ws;               ws += (size_t)(N + 1) * 4;
    int*   blist  = (int*)ws;               ws += (size_t)N * 4;
    int*   partial= (int*)ws;               ws += 1024 * 4;          // N-scan partials
    int*   part1  = (int*)ws;               ws += (size_t)eg * 4;    // E-scan level 1
    int*   part1x = (int*)ws;               ws += (size_t)(eg + 1) * 4;
    int*   part2  = (int*)ws;               /* ws += 1024*4; */      // E-scan level 2

    int* cons2 = ccount;   // alias: ccount dead after pos_kernel
    int* m0e   = lr;       // alias: lr dead after pos_kernel

    // ---- one-time dst-sorted metadata + consumer-CSR build ----
    hipMemsetAsync(count, 0, (size_t)N * 4 + 4, stream);     // count + bcount
    hipMemsetAsync(ccount, 0, (size_t)E * 4, stream);
    rank0_kernel<<<eg, eb, 0, stream>>>(edge_dst, indice, count, ccount, lr, crank, E);
    // N-scan: count -> start
    scan_partial<<<ng, eb, 0, stream>>>(count, partial, N);
    scan_top<<<1, 1024, 0, stream>>>(partial, ng);
    scan_final<<<ng, eb, 0, stream>>>(count, partial, start, N);
    // slots + per-slot consumer counts
    pos_kernel<<<eg, eb, 0, stream>>>(edge_dst, lr, start, ccount, pos, slotcc, E);
    // E-scan: slotcc -> csl (two partial levels since eg > 1024)
    scan_partial<<<eg, eb, 0, stream>>>(slotcc, part1, E);
    scan_partial<<<ng2, eb, 0, stream>>>(part1, part2, eg);
    scan_top<<<1, 1024, 0, stream>>>(part2, ng2);
    scan_final<<<ng2, eb, 0, stream>>>(part1, part2, part1x, eg);
    scan_final<<<eg, eb, 0, stream>>>(slotcc, part1x, csl, E);
    // consumer lists (slot-major) + per-slot meta
    cons_scatter<<<eg, eb, 0, stream>>>(indice, crank, pos, csl, cons2, E);
    scatter_direct<<<eg, eb, 0, stream>>>(a1_src, edge_dst, pos, meta1, m0e, E);
    bnode_build<<<ng, eb, 0, stream>>>(start, blist, bcount, N);

    // ---- DEPTH rounds, marg + t2c double-buffered ----
    u32* t_cur = t2a;
    u32* t_nxt = t2b;
    float* m_in  = marg_b;
    float* m_out = marg_a;
    const int bg = (N * 4 + eb - 1) / eb;

    for (int it = 0; it < DEPTH; ++it) {
        binit<<<bg, eb, 0, stream>>>(blist, bcount, field_i, m_out);
        if (it == 0)
            fused_round<0><<<eg, eb, 0, stream>>>(meta1, m0e, csl, cons2, C, cav_in,
                                                  nullptr, nullptr, start, field_i,
                                                  t_cur, m_out, E);
        else if (it != DEPTH - 1)
            fused_round<1><<<eg, eb, 0, stream>>>(meta1, m0e, csl, cons2, C, nullptr,
                                                  m_in, t_cur, start, field_i,
                                                  t_nxt, m_out, E);
        else
            fused_round<2><<<eg, eb, 0, stream>>>(meta1, m0e, csl, cons2, C, nullptr,
                                                  m_in, t_cur, start, field_i,
                                                  nullptr, m_out, E);
        if (it != 0) { u32* tt = t_cur; t_cur = t_nxt; t_nxt = tt; }
        float* tm = m_in; m_in = m_out; m_out = tm;
    }

    node_out<<<ng, eb, 0, stream>>>(m_in, out, N);
}

// Round 2
// 616.332 us; speedup vs baseline: 1.3263x; 1.3263x over previous
//
#include <hip/hip_runtime.h>
#include <hip/hip_fp16.h>

#define Q 16
#define EPS 1e-8f
#define DEPTH 5
#define BS 512      // fused_round window/block size
#define WSHIFT 9    // log2(BS)

typedef unsigned int u32;
typedef _Float16 h2 __attribute__((ext_vector_type(2)));

__device__ __forceinline__ u32 pack2(float a, float b) {
    __half2 h = __floats2half2_rn(a, b);
    return *(u32*)&h;
}
__device__ __forceinline__ float2 unpack2(u32 u) {
    __half2 h = *(__half2*)&u;
    return __half22float2(h);
}
__device__ __forceinline__ h2 mkh2(float a, float b) {
    h2 v; v[0] = (_Float16)a; v[1] = (_Float16)b; return v;
}

// ---------- one-time build: dst-sorted slot metadata ----------

// lr[e] = local rank of e within its dst; count[n] ends as degree(n).
// count is N*4 bytes (200 KB): L2-resident, atomics are cheap here.
__global__ __launch_bounds__(256) void rank0_kernel(
    const int* __restrict__ dst, int* __restrict__ count,
    int* __restrict__ lr, int E)
{
    int e = blockIdx.x * 256 + threadIdx.x;
    if (e < E) lr[e] = atomicAdd(&count[dst[e]], 1);
}

// --- parallel exclusive scan: count[0..N) -> start[0..N] ---
__global__ __launch_bounds__(256) void scan_partial(
    const int* __restrict__ count, int* __restrict__ partial, int N)
{
    __shared__ int sm[256];
    int i = blockIdx.x * 256 + threadIdx.x;
    sm[threadIdx.x] = (i < N) ? count[i] : 0;
    __syncthreads();
    for (int off = 128; off > 0; off >>= 1) {
        if (threadIdx.x < off) sm[threadIdx.x] += sm[threadIdx.x + off];
        __syncthreads();
    }
    if (threadIdx.x == 0) partial[blockIdx.x] = sm[0];
}

__global__ __launch_bounds__(1024) void scan_top(
    int* __restrict__ partial, int nb)
{
    __shared__ int sm[1024];
    int t = threadIdx.x;
    int v = (t < nb) ? partial[t] : 0;
    sm[t] = v;
    __syncthreads();
    for (int off = 1; off < 1024; off <<= 1) {
        int u = (t >= off) ? sm[t - off] : 0;
        __syncthreads();
        sm[t] += u;
        __syncthreads();
    }
    if (t < nb) partial[t] = sm[t] - v;
}

__global__ __launch_bounds__(256) void scan_final(
    const int* __restrict__ count, const int* __restrict__ partial,
    int* __restrict__ start, int N)
{
    __shared__ int sm[256];
    int i = blockIdx.x * 256 + threadIdx.x;
    int v = (i < N) ? count[i] : 0;
    sm[threadIdx.x] = v;
    __syncthreads();
    for (int off = 1; off < 256; off <<= 1) {
        int u = (threadIdx.x >= off) ? sm[threadIdx.x - off] : 0;
        __syncthreads();
        sm[threadIdx.x] += u;
        __syncthreads();
    }
    int excl = sm[threadIdx.x] - v + partial[blockIdx.x];
    if (i < N) start[i] = excl;
    if (i == N - 1) start[N] = excl + v;
}

// pos[e] = start[dst[e]] + lr[e]
__global__ __launch_bounds__(256) void pos_kernel(
    const int* __restrict__ dst, const int* __restrict__ lr,
    const int* __restrict__ start, int* __restrict__ pos, int E)
{
    int e = blockIdx.x * 256 + threadIdx.x;
    if (e < E) pos[e] = start[dst[e]] + lr[e];
}

// Direct per-slot metadata scatter (replaces sorted[] + meta_pack):
// meta2[pos[e]] = (pos[indice[e]], dst<<16 | src);  m0e[pos[e]] = e
__global__ __launch_bounds__(256) void scatter_direct(
    const int* __restrict__ a1_src, const int* __restrict__ indice,
    const int* __restrict__ dst, const int* __restrict__ pos,
    int2* __restrict__ meta2, int* __restrict__ m0e, int E)
{
    int e = blockIdx.x * 256 + threadIdx.x;
    if (e < E) {
        int p = pos[e];
        meta2[p] = make_int2(pos[indice[e]],
                             (int)(((u32)dst[e] << 16) | (u32)a1_src[e]));
        m0e[p] = e;
    }
}

// boundary nodes: slot range crosses a BS-slot window, or empty.
__global__ __launch_bounds__(256) void bnode_build(
    const int* __restrict__ start, int* __restrict__ blist,
    int* __restrict__ bcount, int N)
{
    int n = blockIdx.x * 256 + threadIdx.x;
    if (n >= N) return;
    int slo = start[n], shi = start[n + 1];
    bool need = (slo == shi) || ((slo >> WSHIFT) != ((shi - 1) >> WSHIFT));
    if (need) {
        int p = atomicAdd(bcount, 1);
        blist[p] = n;
    }
}

// per-round: init only boundary-node rows to field
__global__ __launch_bounds__(256) void binit(
    const int* __restrict__ blist, const int* __restrict__ bcount,
    const float* __restrict__ field, float* __restrict__ marg)
{
    int idx = blockIdx.x * 256 + threadIdx.x;
    int cnt = *bcount;
    if (idx >= cnt * 4) return;
    int n = blist[idx >> 2], part = idx & 3;
    ((float4*)(marg + (size_t)n * Q))[part] =
        ((const float4*)(field + (size_t)n * Q))[part];
}

// ---------- fused per-round kernel ----------
// MODE 0: round 1 (reads cav via m0e), writes t2
// MODE 1: mid rounds (reads marg_in/t2_old via meta2), writes t2
// MODE 2: last round (as 1, skips dead t2 write)
template<int MODE>
__global__ __launch_bounds__(BS) void fused_round(
    const int2* __restrict__ meta2, const int* __restrict__ m0e,
    const float* __restrict__ C,
    const float* __restrict__ cav,
    const float* __restrict__ marg_in, const u32* __restrict__ t2_old,
    const int* __restrict__ start, const float* __restrict__ field,
    u32* __restrict__ t2_new, float* __restrict__ marg_out, int E)
{
    __shared__ __align__(16) h2 Csh[Q * 8];   // column-major fp16
    __shared__ float stage[BS * 17];
    __shared__ int s_nfirst, s_nlast;

    const int tid = threadIdx.x;
    const int blo = blockIdx.x * BS;
    const int bhi = min(blo + BS, E);
    const int j = blo + tid;
    const bool act = (j < E);

    // ---- issue ALL global loads first (overlap latency with LDS staging) ----
    int2 meta;
    float4 m0, m1, m2, m3;
    uint4 r0, r1;
    if (act) {
        meta = meta2[j];
        if (MODE == 0) {
            const float4* rp = (const float4*)(cav + (size_t)m0e[j] * Q);
            m0 = rp[0]; m1 = rp[1]; m2 = rp[2]; m3 = rp[3];
        } else {
            const int src = meta.y & 0xffff;
            const float4* mp = (const float4*)(marg_in + (size_t)src * Q);
            const uint4*  tp = (const uint4*)(t2_old + (size_t)meta.x * 8);
            m0 = mp[0]; m1 = mp[1]; m2 = mp[2]; m3 = mp[3];
            r0 = tp[0]; r1 = tp[1];
        }
    }

    if (tid < 128) {
        int q = tid >> 3, kk = tid & 7;
        Csh[q * 8 + kk] = mkh2(C[(2 * kk) * Q + q], C[(2 * kk + 1) * Q + q]);
    }
    if (act) {
        int mydst = (int)(((u32)meta.y) >> 16);
        if (j == blo)     s_nfirst = mydst;
        if (j == bhi - 1) s_nlast  = mydst;
    }
    __syncthreads();

    float t[Q];
    if (act) {
        h2 uh[8];
        float s, logs;
        if (MODE == 0) {
            uh[0] = mkh2(m0.x, m0.y); uh[1] = mkh2(m0.z, m0.w);
            uh[2] = mkh2(m1.x, m1.y); uh[3] = mkh2(m1.z, m1.w);
            uh[4] = mkh2(m2.x, m2.y); uh[5] = mkh2(m2.z, m2.w);
            uh[6] = mkh2(m3.x, m3.y); uh[7] = mkh2(m3.z, m3.w);
            s = 1.f; logs = 0.f;
        } else {
            float2 p0 = unpack2(r0.x), p1 = unpack2(r0.y),
                   p2 = unpack2(r0.z), p3 = unpack2(r0.w);
            float2 p4 = unpack2(r1.x), p5 = unpack2(r1.y),
                   p6 = unpack2(r1.z), p7 = unpack2(r1.w);

            float x[Q] = {m0.x - p0.x, m0.y - p0.y, m0.z - p1.x, m0.w - p1.y,
                          m1.x - p2.x, m1.y - p2.y, m1.z - p3.x, m1.w - p3.y,
                          m2.x - p4.x, m2.y - p4.y, m2.z - p5.x, m2.w - p5.y,
                          m3.x - p6.x, m3.y - p6.y, m3.z - p7.x, m3.w - p7.y};

            float mx = x[0];
#pragma unroll
            for (int q = 1; q < Q; ++q) mx = fmaxf(mx, x[q]);
            float u[Q];
            s = 0.f;
#pragma unroll
            for (int q = 0; q < Q; ++q) { u[q] = __expf(x[q] - mx); s += u[q]; }
            logs = __logf(s);
#pragma unroll
            for (int k = 0; k < 8; ++k) uh[k] = mkh2(u[2 * k], u[2 * k + 1]);
        }

        const float base = EPS * s;
#pragma unroll
        for (int q = 0; q < Q; ++q) {
            const uint4* cp = (const uint4*)&Csh[q * 8];
            h2 col[8];
            ((uint4*)col)[0] = cp[0];
            ((uint4*)col)[1] = cp[1];
            float acc = base;
#pragma unroll
            for (int kk = 0; kk < 8; ++kk)
                acc = __builtin_amdgcn_fdot2(uh[kk], col[kk], acc, false);
            t[q] = __logf(acc) - logs;
        }

        if (MODE != 2) {
            uint4 w0, w1;
            w0.x = pack2(t[0],  t[1]);  w0.y = pack2(t[2],  t[3]);
            w0.z = pack2(t[4],  t[5]);  w0.w = pack2(t[6],  t[7]);
            w1.x = pack2(t[8],  t[9]);  w1.y = pack2(t[10], t[11]);
            w1.z = pack2(t[12], t[13]); w1.w = pack2(t[14], t[15]);
            uint4* op = (uint4*)(t2_new + (size_t)j * 8);   // coalesced stream
            op[0] = w0; op[1] = w1;
        }
    } else {
#pragma unroll
        for (int q = 0; q < Q; ++q) t[q] = 0.f;
    }

#pragma unroll
    for (int q = 0; q < Q; ++q) stage[tid * 17 + q] = t[q];
    __syncthreads();

    const int nfirst = s_nfirst;
    const int ncnt = s_nlast - nfirst + 1;
    for (int k = tid; k < ncnt * Q; k += BS) {
        int ln = k >> 4, q = k & 15;
        int n = nfirst + ln;
        int slo = start[n], shi = start[n + 1];
        int lo = max(slo, blo), hi = min(shi, bhi);
        float s = 0.f;
        for (int sl = lo; sl < hi; ++sl) s += stage[(sl - blo) * 17 + q];
        if (slo >= blo && shi <= bhi)
            marg_out[(size_t)n * Q + q] = s + field[(size_t)n * Q + q];
        else
            atomicAdd(marg_out + (size_t)n * Q + q, s);
    }
}

// final: per node log_softmax
__global__ __launch_bounds__(256) void node_out(
    const float* __restrict__ marg, float* __restrict__ out, int N)
{
    int i = blockIdx.x * 256 + threadIdx.x;
    if (i >= N) return;

    const float4* mp = (const float4*)(marg + (size_t)i * Q);
    float4 m0 = mp[0], m1 = mp[1], m2 = mp[2], m3 = mp[3];
    float x[Q] = {m0.x, m0.y, m0.z, m0.w, m1.x, m1.y, m1.z, m1.w,
                  m2.x, m2.y, m2.z, m2.w, m3.x, m3.y, m3.z, m3.w};

    float mx = x[0];
#pragma unroll
    for (int q = 1; q < Q; ++q) mx = fmaxf(mx, x[q]);
    float s = 0.f;
#pragma unroll
    for (int q = 0; q < Q; ++q) s += __expf(x[q] - mx);
    float lse = mx + __logf(s);

    float4* op = (float4*)(out + (size_t)i * Q);
    op[0] = make_float4(x[0]  - lse, x[1]  - lse, x[2]  - lse, x[3]  - lse);
    op[1] = make_float4(x[4]  - lse, x[5]  - lse, x[6]  - lse, x[7]  - lse);
    op[2] = make_float4(x[8]  - lse, x[9]  - lse, x[10] - lse, x[11] - lse);
    op[3] = make_float4(x[12] - lse, x[13] - lse, x[14] - lse, x[15] - lse);
}

extern "C" void kernel_launch(void* const* d_in, const int* in_sizes, int n_in,
                              void* d_out, int out_size, void* d_ws, size_t ws_size,
                              hipStream_t stream) {
    // inputs: 0 marg_i (dead), 1 cav_ij, 2 C, 3 field_i, 4 edge_dst, 5 a1_src, 6 indice_ij
    const float* cav_in   = (const float*)d_in[1];
    const float* C        = (const float*)d_in[2];
    const float* field_i  = (const float*)d_in[3];
    const int*   edge_dst = (const int*)d_in[4];
    const int*   a1_src   = (const int*)d_in[5];
    const int*   indice   = (const int*)d_in[6];
    float* out = (float*)d_out;

    const int E = in_sizes[4];
    const int N = in_sizes[0] / Q;

    char* ws = (char*)d_ws;
    const size_t t2_bytes   = (size_t)E * 32;            // fp16 rows, 32B each
    const size_t node_bytes = (size_t)N * Q * sizeof(float);
    u32*   t2a    = (u32*)ws;                     ws += t2_bytes;
    u32*   t2b    = (u32*)ws;                     ws += t2_bytes;
    int2*  meta2  = (int2*)ws;                    ws += (size_t)E * 8;
    int*   m0e    = (int*)ws;                     ws += (size_t)E * 4;
    float* marg_a = (float*)ws;                   ws += node_bytes;
    float* marg_b = (float*)ws;                   ws += node_bytes;
    int*   pos    = (int*)ws;                     ws += (size_t)E * 4;
    int*   lr     = (int*)ws;                     ws += (size_t)E * 4;
    int*   count  = (int*)ws;                     ws += (size_t)N * 4;
    int*   bcount = (int*)ws;                     ws += 4;
    int*   start  = (int*)ws;                     ws += (size_t)(N + 1) * 4;
    int*   blist  = (int*)ws;                     ws += (size_t)N * 4;
    int*   partial= (int*)ws;

    const int eb = 256;
    const int eg = (E + eb - 1) / eb;         // blocks over E (256-thread kernels)
    const int fg = (E + BS - 1) / BS;         // blocks for fused_round
    const int ng = (N + eb - 1) / eb;         // #scan blocks (<=1024 required)

    // ---- one-time dst-sorted metadata build ----
    hipMemsetAsync(count, 0, (size_t)N * 4 + 4, stream);   // count + bcount
    rank0_kernel<<<eg, eb, 0, stream>>>(edge_dst, count, lr, E);
    scan_partial<<<ng, eb, 0, stream>>>(count, partial, N);
    scan_top<<<1, 1024, 0, stream>>>(partial, ng);
    scan_final<<<ng, eb, 0, stream>>>(count, partial, start, N);
    pos_kernel<<<eg, eb, 0, stream>>>(edge_dst, lr, start, pos, E);
    scatter_direct<<<eg, eb, 0, stream>>>(a1_src, indice, edge_dst, pos,
                                          meta2, m0e, E);
    bnode_build<<<ng, eb, 0, stream>>>(start, blist, bcount, N);

    // ---- DEPTH rounds, marg double-buffered ----
    u32* t_cur = t2a;
    u32* t_nxt = t2b;
    float* m_in = marg_b;
    float* m_out = marg_a;
    const int bg = (N * 4 + eb - 1) / eb;

    for (int it = 0; it < DEPTH; ++it) {
        binit<<<bg, eb, 0, stream>>>(blist, bcount, field_i, m_out);
        if (it == 0)
            fused_round<0><<<fg, BS, 0, stream>>>(meta2, m0e, C, cav_in,
                                                  nullptr, nullptr, start, field_i,
                                                  t_cur, m_out, E);
        else if (it != DEPTH - 1)
            fused_round<1><<<fg, BS, 0, stream>>>(meta2, m0e, C, nullptr,
                                                  m_in, t_cur, start, field_i,
                                                  t_nxt, m_out, E);
        else
            fused_round<2><<<fg, BS, 0, stream>>>(meta2, m0e, C, nullptr,
                                                  m_in, t_cur, start, field_i,
                                                  nullptr, m_out, E);
        if (it != 0) { u32* tt = t_cur; t_cur = t_nxt; t_nxt = tt; }
        float* tm = m_in; m_in = m_out; m_out = tm;
    }

    node_out<<<ng, eb, 0, stream>>>(m_in, out, N);
}